// Round 1
// baseline (145.638 us; speedup 1.0000x reference)
//
#include <hip/hip_runtime.h>
#include <cstdint>
#include <cstddef>

typedef float  f32x4 __attribute__((ext_vector_type(4)));
typedef float  f32x2 __attribute__((ext_vector_type(2)));
typedef short  s16x8 __attribute__((ext_vector_type(8)));
typedef short  s16x4 __attribute__((ext_vector_type(4)));
typedef unsigned int u32x4 __attribute__((ext_vector_type(4)));

#define EPSV 1e-5f

__device__ __forceinline__ float rfl(float v) {
  return __builtin_bit_cast(float, __builtin_amdgcn_readfirstlane(__builtin_bit_cast(int, v)));
}
__device__ __forceinline__ unsigned pk2(float a, float b) {
  unsigned short ua = __builtin_bit_cast(unsigned short, (__bf16)a);
  unsigned short ub = __builtin_bit_cast(unsigned short, (__bf16)b);
  return (unsigned)ua | ((unsigned)ub << 16);
}
__device__ __forceinline__ void gll16(const void* g, void* l) {
  __builtin_amdgcn_global_load_lds((const __attribute__((address_space(1))) unsigned int*)g,
                                   (__attribute__((address_space(3))) unsigned int*)l, 16, 0, 0);
}
__device__ __forceinline__ f32x4 relu4(f32x4 v) {
  f32x4 r; r.x = fmaxf(v.x,0.f); r.y = fmaxf(v.y,0.f); r.z = fmaxf(v.z,0.f); r.w = fmaxf(v.w,0.f);
  return r;
}

// ---------------- kernel F: fold BN-o into Wo, emit bf16 in fragment layout ----------------
// Wo''(element) = chunk(mt*8+kt)*10240 + kk*5120 + ocl*40 + g*8 + jj
//   (40-element = 80B row stride per oc -> conflict-free ds_read_b128 A-frags)
__global__ void kF(const float* __restrict__ wo, const float* __restrict__ bo,
                   const float* __restrict__ go, const float* __restrict__ beo,
                   const float* __restrict__ mo, const float* __restrict__ vo,
                   __bf16* __restrict__ wopp, float* __restrict__ co)
{
  const int oc = blockIdx.x;   // 0..511
  const int k  = threadIdx.x;  // 0..511
  float invo = go[oc] * rsqrtf(vo[oc] + EPSV);
  float v = wo[(size_t)oc*512 + k] * invo;
  int mt = oc >> 7, ocl = oc & 127;
  int kt = k >> 6, kk = (k >> 5) & 1, g = (k >> 3) & 3, jj = k & 7;
  size_t dst = (size_t)(mt*8 + kt)*10240 + (size_t)kk*5120 + ocl*40 + g*8 + jj;
  wopp[dst] = (__bf16)v;
  if (k == 0) co[oc] = bo[oc]*invo + beo[oc] - mo[oc]*invo;
}

// ---------------- kernel A: 4 dilated depthwise convs + BN + ReLU + 4x4 mix + BN + ReLU ----
// block = one (b,c); 4 full 96x96 planes staged in LDS; z2 out layout [b][c][pix][o] (bf16)
__global__ __launch_bounds__(1024) void kA(const float* __restrict__ x,
    const float* __restrict__ wdw, const float* __restrict__ bdw, const float* __restrict__ gdw,
    const float* __restrict__ bedw, const float* __restrict__ mdw, const float* __restrict__ vdw,
    const float* __restrict__ w4, const float* __restrict__ bsc, const float* __restrict__ gsc,
    const float* __restrict__ besc, const float* __restrict__ msc, const float* __restrict__ vsc,
    __bf16* __restrict__ z2s)
{
  __shared__ alignas(16) float lds[32 + 4*9216 + 32];   // guard for +-18 row-edge reads
  const int tid = threadIdx.x;
  const int b = blockIdx.x >> 7, c = blockIdx.x & 127;

  { // stage 4 planes (x channels i*128+c), float4-coalesced
    const f32x4* xv = (const f32x4*)x;
    f32x4* lv = (f32x4*)(lds + 32);
    const size_t base = (size_t)(b*512 + c) * 2304;
    #pragma unroll
    for (int kq = 0; kq < 9; ++kq) {
      int j = tid + kq*1024;          // 0..9215
      int i = j / 2304;
      int off = j - i*2304;
      lv[j] = xv[base + (size_t)i*128*2304 + off];
    }
  }

  // uniform folded params (readfirstlane -> SGPRs)
  float wf[4][9], cdwv[4], w4f[4][4], c4v[4];
  #pragma unroll
  for (int i = 0; i < 4; ++i) {
    int idx = i*128 + c;
    float inv = gdw[idx] * rsqrtf(vdw[idx] + EPSV);
    #pragma unroll
    for (int t = 0; t < 9; ++t) wf[i][t] = rfl(wdw[(size_t)idx*9 + t] * inv);
    cdwv[i] = rfl(bdw[idx]*inv + bedw[idx] - mdw[idx]*inv);
  }
  #pragma unroll
  for (int o = 0; o < 4; ++o) {
    float invs = gsc[o] * rsqrtf(vsc[o] + EPSV);
    #pragma unroll
    for (int i = 0; i < 4; ++i) w4f[o][i] = rfl(w4[o*4 + i] * invs);
    c4v[o] = rfl(bsc[o]*invs + besc[o] - msc[o]*invs);
  }

  __syncthreads();

  const int RR[4] = {1, 6, 12, 18};
  __bf16* zbase = z2s + (size_t)(b*128 + c) * 36864;

  for (int q = tid; q < 2304; q += 1024) {   // quad = 4 horizontal pixels
    int h = q / 24;
    int w0 = (q - h*24) * 4;
    f32x4 y[4];
    #pragma unroll
    for (int i = 0; i < 4; ++i) {
      const int r = RR[i];
      f32x4 mL, mR;   // horizontal zero-pad masks
      #pragma unroll
      for (int j = 0; j < 4; ++j) {
        mL[j] = (w0 + j - r >= 0) ? 1.f : 0.f;
        mR[j] = (w0 + j + r <= 95) ? 1.f : 0.f;
      }
      f32x4 acc = {0.f, 0.f, 0.f, 0.f};
      #pragma unroll
      for (int dh = -1; dh <= 1; ++dh) {
        int h2 = h + dh*r;
        if ((unsigned)h2 < 96u) {
          const float* row = lds + 32 + i*9216 + h2*96 + w0;
          f32x4 tc = *(const f32x4*)row;
          f32x4 tl, tr;
          if (r == 1) {
            float sm = row[-1], sp = row[4];
            tl = (f32x4){sm, tc.x, tc.y, tc.z};
            tr = (f32x4){tc.y, tc.z, tc.w, sp};
          } else if (r == 12) {
            tl = *(const f32x4*)(row - 12);
            tr = *(const f32x4*)(row + 12);
          } else { // r = 6 or 18: 8B-aligned
            f32x2 a0 = *(const f32x2*)(row - r);
            f32x2 a1 = *(const f32x2*)(row - r + 2);
            f32x2 b0 = *(const f32x2*)(row + r);
            f32x2 b1 = *(const f32x2*)(row + r + 2);
            tl = (f32x4){a0.x, a0.y, a1.x, a1.y};
            tr = (f32x4){b0.x, b0.y, b1.x, b1.y};
          }
          const int wb = (dh + 1) * 3;
          acc += wf[i][wb+0]*(tl*mL) + wf[i][wb+1]*tc + wf[i][wb+2]*(tr*mR);
        }
      }
      y[i] = relu4(acc + cdwv[i]);
    }
    f32x4 z[4];
    #pragma unroll
    for (int o = 0; o < 4; ++o) {
      f32x4 t = {c4v[o], c4v[o], c4v[o], c4v[o]};
      #pragma unroll
      for (int i = 0; i < 4; ++i) t += w4f[o][i]*y[i];
      z[o] = relu4(t);
    }
    // memory order: [pix][o], 16 bf16 = 32B contiguous
    u32x4 s0 = { pk2(z[0].x,z[1].x), pk2(z[2].x,z[3].x), pk2(z[0].y,z[1].y), pk2(z[2].y,z[3].y) };
    u32x4 s1 = { pk2(z[0].z,z[1].z), pk2(z[2].z,z[3].z), pk2(z[0].w,z[1].w), pk2(z[2].w,z[3].w) };
    u32x4* dst = (u32x4*)(zbase + (size_t)q*16);
    dst[0] = s0;
    dst[1] = s1;
  }
}

// ---------------- kernel B: out = ReLU(Wo'' @ z2 + co), bf16 MFMA, m97 structure -----------
// tile 128(oc) x 128(pix), BK=64, 4 waves (2x2), 16x16x32 bf16 MFMA
__global__ __launch_bounds__(256) void kB(const void* __restrict__ wopp_,
    const void* __restrict__ z2s_, const float* __restrict__ co, float* __restrict__ out)
{
  __shared__ alignas(16) char lA[20480];
  __shared__ alignas(16) char lB[16384];
  const char* wopp = (const char*)wopp_;
  const char* z2s  = (const char*)z2s_;

  const int tid = threadIdx.x;
  const int lane = tid & 63, wv = tid >> 6;
  const int wm = wv >> 1, wn = wv & 1;
  const int pt = blockIdx.x;      // 0..71 pixel tiles
  const int mt = blockIdx.y;      // 0..3  oc tiles
  const int b  = blockIdx.z;      // 0..7
  const int pix0 = pt * 128;
  const int l15 = lane & 15, lg = lane >> 4;

  f32x4 acc[4][4] = {};

  for (int kt = 0; kt < 8; ++kt) {
    // stage A: chunk (mt,kt) = 20KB linear
    const char* srcA = wopp + (size_t)(mt*8 + kt)*20480;
    for (int j = wv; j < 20; j += 4)
      gll16(srcA + j*1024 + lane*16, lA + j*1024);
    // stage B: 16 x 1KB (one per c in [kt*16, kt*16+16))
    #pragma unroll
    for (int ct4 = 0; ct4 < 4; ++ct4) {
      int ct = wv*4 + ct4;
      const char* srcB = z2s + ((size_t)(b*128 + kt*16 + ct)*36864 + (size_t)pix0*4)*2;
      gll16(srcB + lane*16, lB + ct*1024);
    }
    __syncthreads();

    #pragma unroll
    for (int kk = 0; kk < 2; ++kk) {
      s16x8 af[4];
      #pragma unroll
      for (int m = 0; m < 4; ++m)
        af[m] = *(const s16x8*)(lA + kk*10240 + (wm*64 + m*16 + l15)*80 + lg*16);
      #pragma unroll
      for (int n = 0; n < 4; ++n) {
        const char* p = lB + kk*8192 + lg*2048 + (wn*64 + n*16 + l15)*8;
        s16x4 lo = *(const s16x4*)(p);
        s16x4 hi = *(const s16x4*)(p + 1024);
        s16x8 bfr = __builtin_shufflevector(lo, hi, 0,1,2,3,4,5,6,7);
        #pragma unroll
        for (int m = 0; m < 4; ++m)
          acc[m][n] = __builtin_amdgcn_mfma_f32_16x16x32_bf16(af[m], bfr, acc[m][n], 0, 0, 0);
      }
    }
    __syncthreads();
  }

  // epilogue: + folded bias, ReLU, coalesced fp32 stores
  const int colp = pix0 + wn*64 + l15;
  #pragma unroll
  for (int m = 0; m < 4; ++m) {
    const int ocb = mt*128 + wm*64 + m*16 + lg*4;
    #pragma unroll
    for (int r2 = 0; r2 < 4; ++r2) {
      const int oc = ocb + r2;
      const float cov = co[oc];
      float* orow = out + ((size_t)(b*512 + oc))*9216 + colp;
      #pragma unroll
      for (int n = 0; n < 4; ++n) {
        float v = acc[m][n][r2] + cov;
        orow[(size_t)n*16] = fmaxf(v, 0.f);
      }
    }
  }
}

extern "C" void kernel_launch(void* const* d_in, const int* in_sizes, int n_in,
                              void* d_out, int out_size, void* d_ws, size_t ws_size,
                              hipStream_t stream)
{
  (void)in_sizes; (void)out_size;
  if (n_in < 19) return;
  const size_t Z2_BYTES = 75497472;      // 8*512*9216 bf16
  const size_t WOPP_BYTES = 655360;      // 32 chunks * 20480
  if (ws_size < Z2_BYTES + WOPP_BYTES + 2048) return;  // keep poisoned -> visible failure

  const float* x    = (const float*)d_in[0];
  const float* wdw  = (const float*)d_in[1];
  const float* bdw  = (const float*)d_in[2];
  const float* gdw  = (const float*)d_in[3];
  const float* bedw = (const float*)d_in[4];
  const float* mdw  = (const float*)d_in[5];
  const float* vdw  = (const float*)d_in[6];
  const float* w4   = (const float*)d_in[7];
  const float* bs   = (const float*)d_in[8];
  const float* gs   = (const float*)d_in[9];
  const float* bes  = (const float*)d_in[10];
  const float* ms   = (const float*)d_in[11];
  const float* vs   = (const float*)d_in[12];
  const float* wo   = (const float*)d_in[13];
  const float* bo   = (const float*)d_in[14];
  const float* go   = (const float*)d_in[15];
  const float* beo  = (const float*)d_in[16];
  const float* mo   = (const float*)d_in[17];
  const float* vo   = (const float*)d_in[18];

  __bf16* z2s  = (__bf16*)d_ws;
  __bf16* wopp = (__bf16*)((char*)d_ws + Z2_BYTES);
  float*  co   = (float*)((char*)d_ws + Z2_BYTES + WOPP_BYTES);

  kF<<<512, 512, 0, stream>>>(wo, bo, go, beo, mo, vo, wopp, co);
  kA<<<1024, 1024, 0, stream>>>(x, wdw, bdw, gdw, bedw, mdw, vdw, w4, bs, gs, bes, ms, vs, z2s);
  kB<<<dim3(72, 4, 8), 256, 0, stream>>>(wopp, z2s, co, (float*)d_out);
}

// Round 2
// 129.912 us; speedup vs baseline: 1.1211x; 1.1211x over previous
//
#include <hip/hip_runtime.h>
#include <cstdint>
#include <cstddef>

typedef float  f32x4 __attribute__((ext_vector_type(4)));
typedef float  f32x2 __attribute__((ext_vector_type(2)));
typedef short  s16x8 __attribute__((ext_vector_type(8)));
typedef short  s16x4 __attribute__((ext_vector_type(4)));
typedef unsigned int u32x4 __attribute__((ext_vector_type(4)));
typedef unsigned int u32x2 __attribute__((ext_vector_type(2)));

#define EPSV 1e-5f

__device__ __forceinline__ float rfl(float v) {
  return __builtin_bit_cast(float, __builtin_amdgcn_readfirstlane(__builtin_bit_cast(int, v)));
}
__device__ __forceinline__ unsigned pk2(float a, float b) {
  unsigned short ua = __builtin_bit_cast(unsigned short, (__bf16)a);
  unsigned short ub = __builtin_bit_cast(unsigned short, (__bf16)b);
  return (unsigned)ua | ((unsigned)ub << 16);
}
__device__ __forceinline__ float bf2f(unsigned short u) {
  return __builtin_bit_cast(float, (unsigned)u << 16);
}
__device__ __forceinline__ f32x2 ub2f(unsigned u) {
  f32x2 r;
  r.x = __builtin_bit_cast(float, u << 16);
  r.y = __builtin_bit_cast(float, u & 0xffff0000u);
  return r;
}
__device__ __forceinline__ void gll16(const void* g, void* l) {
  __builtin_amdgcn_global_load_lds((const __attribute__((address_space(1))) unsigned int*)g,
                                   (__attribute__((address_space(3))) unsigned int*)l, 16, 0, 0);
}
__device__ __forceinline__ f32x4 relu4(f32x4 v) {
  f32x4 r; r.x = fmaxf(v.x,0.f); r.y = fmaxf(v.y,0.f); r.z = fmaxf(v.z,0.f); r.w = fmaxf(v.w,0.f);
  return r;
}

// ---------------- kernel F: fold BN-o into Wo, emit bf16 in fragment layout ----------------
__global__ void kF(const float* __restrict__ wo, const float* __restrict__ bo,
                   const float* __restrict__ go, const float* __restrict__ beo,
                   const float* __restrict__ mo, const float* __restrict__ vo,
                   __bf16* __restrict__ wopp, float* __restrict__ co)
{
  const int oc = blockIdx.x;   // 0..511
  const int k  = threadIdx.x;  // 0..511
  float invo = go[oc] * rsqrtf(vo[oc] + EPSV);
  float v = wo[(size_t)oc*512 + k] * invo;
  int mt = oc >> 7, ocl = oc & 127;
  int kt = k >> 6, kk = (k >> 5) & 1, g = (k >> 3) & 3, jj = k & 7;
  size_t dst = (size_t)(mt*8 + kt)*10240 + (size_t)kk*5120 + ocl*40 + g*8 + jj;
  wopp[dst] = (__bf16)v;
  if (k == 0) co[oc] = bo[oc]*invo + beo[oc] - mo[oc]*invo;
}

// ---------------- kernel A: 4 dilated depthwise convs + BN + ReLU + 4x4 mix + BN + ReLU ----
// block = one (b,c); 4 full 96x96 planes staged in LDS as bf16 (73.9 KB -> 2 blocks/CU)
__global__ __launch_bounds__(1024, 8) void kA(const float* __restrict__ x,
    const float* __restrict__ wdw, const float* __restrict__ bdw, const float* __restrict__ gdw,
    const float* __restrict__ bedw, const float* __restrict__ mdw, const float* __restrict__ vdw,
    const float* __restrict__ w4, const float* __restrict__ bsc, const float* __restrict__ gsc,
    const float* __restrict__ besc, const float* __restrict__ msc, const float* __restrict__ vsc,
    __bf16* __restrict__ z2s)
{
  __shared__ alignas(16) unsigned short sx[64 + 4*9216 + 64];   // bf16, zeroed guards
  const int tid = threadIdx.x;
  const int b = blockIdx.x >> 7, c = blockIdx.x & 127;

  { // stage 4 planes (x channels i*128+c): f32x4 load -> packed bf16 -> 8B LDS write
    const f32x4* xv = (const f32x4*)x;
    unsigned* lv = (unsigned*)(sx + 64);
    const size_t base = (size_t)(b*512 + c) * 2304;
    #pragma unroll
    for (int kq = 0; kq < 9; ++kq) {
      int j = tid + kq*1024;          // f32x4 index 0..9215
      int i = j / 2304;
      int off = j - i*2304;
      f32x4 v = xv[base + (size_t)i*128*2304 + off];
      u32x2 w; w.x = pk2(v.x, v.y); w.y = pk2(v.z, v.w);
      *(u32x2*)(lv + 2*j) = w;
    }
    if (tid < 64) { sx[tid] = 0; sx[64 + 4*9216 + tid] = 0; }
  }

  // uniform folded params (readfirstlane -> SGPRs)
  float wf[4][9], cdwv[4], w4f[4][4], c4v[4];
  #pragma unroll
  for (int i = 0; i < 4; ++i) {
    int idx = i*128 + c;
    float inv = gdw[idx] * rsqrtf(vdw[idx] + EPSV);
    #pragma unroll
    for (int t = 0; t < 9; ++t) wf[i][t] = rfl(wdw[(size_t)idx*9 + t] * inv);
    cdwv[i] = rfl(bdw[idx]*inv + bedw[idx] - mdw[idx]*inv);
  }
  #pragma unroll
  for (int o = 0; o < 4; ++o) {
    float invs = gsc[o] * rsqrtf(vsc[o] + EPSV);
    #pragma unroll
    for (int i = 0; i < 4; ++i) w4f[o][i] = rfl(w4[o*4 + i] * invs);
    c4v[o] = rfl(bsc[o]*invs + besc[o] - msc[o]*invs);
  }

  __syncthreads();

  const int RR[4] = {1, 6, 12, 18};
  __bf16* zbase = z2s + (size_t)(b*128 + c) * 36864;

  for (int q = tid; q < 2304; q += 1024) {   // quad = 4 horizontal pixels
    int h = q / 24;
    int w0 = (q - h*24) * 4;
    f32x4 y[4];
    #pragma unroll
    for (int i = 0; i < 4; ++i) {
      const int r = RR[i];
      // packed-word edge masks (element j of tl valid iff w0+j-r>=0; tr iff w0+j+r<=95)
      unsigned mlw[2], mrw[2];
      #pragma unroll
      for (int jw = 0; jw < 2; ++jw) {
        unsigned m = 0;
        if (w0 + 2*jw     - r >= 0) m |= 0x0000ffffu;
        if (w0 + 2*jw + 1 - r >= 0) m |= 0xffff0000u;
        mlw[jw] = m;
        unsigned m2 = 0;
        if (w0 + 2*jw     + r <= 95) m2 |= 0x0000ffffu;
        if (w0 + 2*jw + 1 + r <= 95) m2 |= 0xffff0000u;
        mrw[jw] = m2;
      }
      f32x4 acc = {0.f, 0.f, 0.f, 0.f};
      #pragma unroll
      for (int dh = -1; dh <= 1; ++dh) {
        int h2 = h + dh*r;
        if ((unsigned)h2 < 96u) {
          const unsigned short* row = sx + 64 + i*9216 + h2*96 + w0;
          const unsigned* pc = (const unsigned*)row;
          unsigned c0 = pc[0], c1 = pc[1];
          f32x2 c01 = ub2f(c0), c23 = ub2f(c1);
          f32x4 tc = {c01.x, c01.y, c23.x, c23.y};
          f32x4 tl, tr;
          if (r == 1) {
            float sm = (w0 >= 1)  ? bf2f(row[-1]) : 0.f;
            float sp = (w0 <= 91) ? bf2f(row[4])  : 0.f;
            tl = (f32x4){sm, tc.x, tc.y, tc.z};
            tr = (f32x4){tc.y, tc.z, tc.w, sp};
          } else {
            const unsigned* pa = (const unsigned*)(row - r);   // (w0-r) even -> 4B aligned
            const unsigned* pb = (const unsigned*)(row + r);
            f32x2 a01 = ub2f(pa[0] & mlw[0]), a23 = ub2f(pa[1] & mlw[1]);
            f32x2 b01 = ub2f(pb[0] & mrw[0]), b23 = ub2f(pb[1] & mrw[1]);
            tl = (f32x4){a01.x, a01.y, a23.x, a23.y};
            tr = (f32x4){b01.x, b01.y, b23.x, b23.y};
          }
          const int wb = (dh + 1) * 3;
          acc += wf[i][wb+0]*tl + wf[i][wb+1]*tc + wf[i][wb+2]*tr;
        }
      }
      y[i] = relu4(acc + cdwv[i]);
    }
    f32x4 z[4];
    #pragma unroll
    for (int o = 0; o < 4; ++o) {
      f32x4 t = {c4v[o], c4v[o], c4v[o], c4v[o]};
      #pragma unroll
      for (int i = 0; i < 4; ++i) t += w4f[o][i]*y[i];
      z[o] = relu4(t);
    }
    // memory order: [pix][o], 16 bf16 = 32B contiguous
    u32x4 s0 = { pk2(z[0].x,z[1].x), pk2(z[2].x,z[3].x), pk2(z[0].y,z[1].y), pk2(z[2].y,z[3].y) };
    u32x4 s1 = { pk2(z[0].z,z[1].z), pk2(z[2].z,z[3].z), pk2(z[0].w,z[1].w), pk2(z[2].w,z[3].w) };
    u32x4* dst = (u32x4*)(zbase + (size_t)q*16);
    dst[0] = s0;
    dst[1] = s1;
  }

  // fix r=1 edge mask for w0=92 case in packed store path (handled above via sp mask)
}

// ---------------- kernel B: out = ReLU(Wo'' @ z2 + co), bf16 MFMA, m97 structure -----------
__global__ __launch_bounds__(256) void kB(const void* __restrict__ wopp_,
    const void* __restrict__ z2s_, const float* __restrict__ co, float* __restrict__ out)
{
  __shared__ alignas(16) char lA[20480];
  __shared__ alignas(16) char lB[16384];
  const char* wopp = (const char*)wopp_;
  const char* z2s  = (const char*)z2s_;

  const int tid = threadIdx.x;
  const int lane = tid & 63, wv = tid >> 6;
  const int wm = wv >> 1, wn = wv & 1;
  const int pt = blockIdx.x;      // 0..71 pixel tiles
  const int mt = blockIdx.y;      // 0..3  oc tiles
  const int b  = blockIdx.z;      // 0..7
  const int pix0 = pt * 128;
  const int l15 = lane & 15, lg = lane >> 4;

  f32x4 acc[4][4] = {};

  for (int kt = 0; kt < 8; ++kt) {
    const char* srcA = wopp + (size_t)(mt*8 + kt)*20480;
    for (int j = wv; j < 20; j += 4)
      gll16(srcA + j*1024 + lane*16, lA + j*1024);
    #pragma unroll
    for (int ct4 = 0; ct4 < 4; ++ct4) {
      int ct = wv*4 + ct4;
      const char* srcB = z2s + ((size_t)(b*128 + kt*16 + ct)*36864 + (size_t)pix0*4)*2;
      gll16(srcB + lane*16, lB + ct*1024);
    }
    __syncthreads();

    #pragma unroll
    for (int kk = 0; kk < 2; ++kk) {
      s16x8 af[4];
      #pragma unroll
      for (int m = 0; m < 4; ++m)
        af[m] = *(const s16x8*)(lA + kk*10240 + (wm*64 + m*16 + l15)*80 + lg*16);
      #pragma unroll
      for (int n = 0; n < 4; ++n) {
        const char* p = lB + kk*8192 + lg*2048 + (wn*64 + n*16 + l15)*8;
        s16x4 lo = *(const s16x4*)(p);
        s16x4 hi = *(const s16x4*)(p + 1024);
        s16x8 bfr = __builtin_shufflevector(lo, hi, 0,1,2,3,4,5,6,7);
        #pragma unroll
        for (int m = 0; m < 4; ++m)
          acc[m][n] = __builtin_amdgcn_mfma_f32_16x16x32_bf16(af[m], bfr, acc[m][n], 0, 0, 0);
      }
    }
    __syncthreads();
  }

  const int colp = pix0 + wn*64 + l15;
  #pragma unroll
  for (int m = 0; m < 4; ++m) {
    const int ocb = mt*128 + wm*64 + m*16 + lg*4;
    #pragma unroll
    for (int r2 = 0; r2 < 4; ++r2) {
      const int oc = ocb + r2;
      const float cov = co[oc];
      float* orow = out + ((size_t)(b*512 + oc))*9216 + colp;
      #pragma unroll
      for (int n = 0; n < 4; ++n) {
        float v = acc[m][n][r2] + cov;
        orow[(size_t)n*16] = fmaxf(v, 0.f);
      }
    }
  }
}

extern "C" void kernel_launch(void* const* d_in, const int* in_sizes, int n_in,
                              void* d_out, int out_size, void* d_ws, size_t ws_size,
                              hipStream_t stream)
{
  (void)in_sizes; (void)out_size;
  if (n_in < 19) return;
  const size_t Z2_BYTES = 75497472;      // 8*512*9216 bf16
  const size_t WOPP_BYTES = 655360;      // 32 chunks * 20480
  if (ws_size < Z2_BYTES + WOPP_BYTES + 2048) return;

  const float* x    = (const float*)d_in[0];
  const float* wdw  = (const float*)d_in[1];
  const float* bdw  = (const float*)d_in[2];
  const float* gdw  = (const float*)d_in[3];
  const float* bedw = (const float*)d_in[4];
  const float* mdw  = (const float*)d_in[5];
  const float* vdw  = (const float*)d_in[6];
  const float* w4   = (const float*)d_in[7];
  const float* bs   = (const float*)d_in[8];
  const float* gs   = (const float*)d_in[9];
  const float* bes  = (const float*)d_in[10];
  const float* ms   = (const float*)d_in[11];
  const float* vs   = (const float*)d_in[12];
  const float* wo   = (const float*)d_in[13];
  const float* bo   = (const float*)d_in[14];
  const float* go   = (const float*)d_in[15];
  const float* beo  = (const float*)d_in[16];
  const float* mo   = (const float*)d_in[17];
  const float* vo   = (const float*)d_in[18];

  __bf16* z2s  = (__bf16*)d_ws;
  __bf16* wopp = (__bf16*)((char*)d_ws + Z2_BYTES);
  float*  co   = (float*)((char*)d_ws + Z2_BYTES + WOPP_BYTES);

  kF<<<512, 512, 0, stream>>>(wo, bo, go, beo, mo, vo, wopp, co);
  kA<<<1024, 1024, 0, stream>>>(x, wdw, bdw, gdw, bedw, mdw, vdw, w4, bs, gs, bes, ms, vs, z2s);
  kB<<<dim3(72, 4, 8), 256, 0, stream>>>(wopp, z2s, co, (float*)d_out);
}

// Round 3
// 120.818 us; speedup vs baseline: 1.2054x; 1.0753x over previous
//
#include <hip/hip_runtime.h>
#include <cstdint>
#include <cstddef>

typedef float  f32x4 __attribute__((ext_vector_type(4)));
typedef float  f32x2 __attribute__((ext_vector_type(2)));
typedef short  s16x8 __attribute__((ext_vector_type(8)));
typedef short  s16x4 __attribute__((ext_vector_type(4)));
typedef unsigned int u32x4 __attribute__((ext_vector_type(4)));
typedef unsigned int u32x2 __attribute__((ext_vector_type(2)));

#define EPSV 1e-5f

__device__ __forceinline__ float rfl(float v) {
  return __builtin_bit_cast(float, __builtin_amdgcn_readfirstlane(__builtin_bit_cast(int, v)));
}
__device__ __forceinline__ unsigned pk2(float a, float b) {
  unsigned short ua = __builtin_bit_cast(unsigned short, (__bf16)a);
  unsigned short ub = __builtin_bit_cast(unsigned short, (__bf16)b);
  return (unsigned)ua | ((unsigned)ub << 16);
}
__device__ __forceinline__ float bf2f(unsigned short u) {
  return __builtin_bit_cast(float, (unsigned)u << 16);
}
__device__ __forceinline__ f32x2 ub2f(unsigned u) {
  f32x2 r;
  r.x = __builtin_bit_cast(float, u << 16);
  r.y = __builtin_bit_cast(float, u & 0xffff0000u);
  return r;
}
__device__ __forceinline__ void gll16(const void* g, void* l) {
  __builtin_amdgcn_global_load_lds((const __attribute__((address_space(1))) unsigned int*)g,
                                   (__attribute__((address_space(3))) unsigned int*)l, 16, 0, 0);
}
__device__ __forceinline__ f32x4 relu4(f32x4 v) {
  f32x4 r; r.x = fmaxf(v.x,0.f); r.y = fmaxf(v.y,0.f); r.z = fmaxf(v.z,0.f); r.w = fmaxf(v.w,0.f);
  return r;
}

// ---------------- kernel F: fold BN-o into Wo, emit bf16 in fragment layout ----------------
__global__ void kF(const float* __restrict__ wo, const float* __restrict__ bo,
                   const float* __restrict__ go, const float* __restrict__ beo,
                   const float* __restrict__ mo, const float* __restrict__ vo,
                   __bf16* __restrict__ wopp, float* __restrict__ co)
{
  const int oc = blockIdx.x;   // 0..511
  const int k  = threadIdx.x;  // 0..511
  float invo = go[oc] * rsqrtf(vo[oc] + EPSV);
  float v = wo[(size_t)oc*512 + k] * invo;
  int mt = oc >> 7, ocl = oc & 127;
  int kt = k >> 6, kk = (k >> 5) & 1, g = (k >> 3) & 3, jj = k & 7;
  size_t dst = (size_t)(mt*8 + kt)*10240 + (size_t)kk*5120 + ocl*40 + g*8 + jj;
  wopp[dst] = (__bf16)v;
  if (k == 0) co[oc] = bo[oc]*invo + beo[oc] - mo[oc]*invo;
}

// ---------------- kernel A: 4 dilated depthwise convs + BN + ReLU + 4x4 mix + BN + ReLU ----
// block = one (b,c); 768 threads, thread owns 3 vertically-adjacent 4-pixel quads (same w0)
// 4 planes staged in LDS as bf16 (74 KB -> 2 blocks/CU); VGPR cap 85 (6 waves/EU)
__global__ __launch_bounds__(768, 6) void kA(const float* __restrict__ x,
    const float* __restrict__ wdw, const float* __restrict__ bdw, const float* __restrict__ gdw,
    const float* __restrict__ bedw, const float* __restrict__ mdw, const float* __restrict__ vdw,
    const float* __restrict__ w4, const float* __restrict__ bsc, const float* __restrict__ gsc,
    const float* __restrict__ besc, const float* __restrict__ msc, const float* __restrict__ vsc,
    __bf16* __restrict__ z2s)
{
  __shared__ alignas(16) unsigned short sx[64 + 4*9216 + 64];   // bf16 planes + guards
  const int tid = threadIdx.x;
  const int b = blockIdx.x >> 7, c = blockIdx.x & 127;

  { // stage 4 planes (x channels i*128+c): f32x4 load -> packed bf16 -> 8B LDS write
    const f32x4* xv = (const f32x4*)x;
    unsigned* lv = (unsigned*)(sx + 64);
    const size_t base = (size_t)(b*512 + c) * 2304;
    #pragma unroll
    for (int kq = 0; kq < 12; ++kq) {
      int j = tid + kq*768;           // f32x4 index 0..9215, exact
      int ii = j / 2304;
      int off = j - ii*2304;
      f32x4 v = xv[base + (size_t)ii*294912 + off];
      u32x2 w; w.x = pk2(v.x, v.y); w.y = pk2(v.z, v.w);
      *(u32x2*)(lv + 2*j) = w;
    }
    if (tid < 64) { sx[tid] = 0; sx[64 + 4*9216 + tid] = 0; }
  }

  // uniform folded params (readfirstlane -> SGPRs)
  float wf[4][9], cdwv[4], w4f[4][4], c4v[4];
  #pragma unroll
  for (int i = 0; i < 4; ++i) {
    int idx = i*128 + c;
    float inv = gdw[idx] * rsqrtf(vdw[idx] + EPSV);
    #pragma unroll
    for (int t = 0; t < 9; ++t) wf[i][t] = rfl(wdw[(size_t)idx*9 + t] * inv);
    cdwv[i] = rfl(bdw[idx]*inv + bedw[idx] - mdw[idx]*inv);
  }
  #pragma unroll
  for (int o = 0; o < 4; ++o) {
    float invs = gsc[o] * rsqrtf(vsc[o] + EPSV);
    #pragma unroll
    for (int i = 0; i < 4; ++i) w4f[o][i] = rfl(w4[o*4 + i] * invs);
    c4v[o] = rfl(bsc[o]*invs + besc[o] - msc[o]*invs);
  }

  __syncthreads();

  const int wq = tid % 24;
  const int hb = (tid / 24) * 3;      // 32 h-groups * 3 rows = 96
  const int w0 = wq * 4;
  __bf16* zbase = z2s + (size_t)(b*128 + c) * 36864;

  const int RR[4] = {1, 6, 12, 18};
  // per-thread edge masks, even-r branches only (both halves of a packed word share the cond)
  unsigned mlw[4][2], mrw[4][2];
  #pragma unroll
  for (int i = 1; i < 4; ++i) {
    const int r = RR[i];
    mlw[i][0] = (w0     >= r)  ? 0xffffffffu : 0u;
    mlw[i][1] = (w0 + 2 >= r)  ? 0xffffffffu : 0u;
    mrw[i][0] = (w0 + r     <= 94) ? 0xffffffffu : 0u;
    mrw[i][1] = (w0 + 2 + r <= 94) ? 0xffffffffu : 0u;
  }
  const bool eL = (w0 >= 1), eR = (w0 <= 91);

  for (int k = 0; k < 3; ++k) {
    const int h = hb + k;
    f32x4 y[4];
    #pragma unroll
    for (int i = 0; i < 4; ++i) {
      const int r = RR[i];
      const unsigned short* pl = sx + 64 + i*9216 + w0;
      f32x4 acc = {0.f, 0.f, 0.f, 0.f};
      #pragma unroll
      for (int dh = -1; dh <= 1; ++dh) {
        const int h2 = h + dh*r;
        if ((unsigned)h2 < 96u) {
          const unsigned short* row = pl + h2*96;
          u32x2 cw = *(const u32x2*)row;            // 8B-aligned (w0%4==0)
          f32x2 c01 = ub2f(cw.x), c23 = ub2f(cw.y);
          f32x4 tc = {c01.x, c01.y, c23.x, c23.y};
          f32x4 tl, tr;
          if (i == 0) {                              // r=1: build from tc + 2 scalar edges
            float sm = eL ? bf2f(row[-1]) : 0.f;
            float sp = eR ? bf2f(row[4])  : 0.f;
            tl = (f32x4){sm, tc.x, tc.y, tc.z};
            tr = (f32x4){tc.y, tc.z, tc.w, sp};
          } else {                                   // even r: 4B loads (w0-r may be %4==2)
            const unsigned* pa = (const unsigned*)(row - r);
            const unsigned* pb = (const unsigned*)(row + r);
            f32x2 a01 = ub2f(pa[0] & mlw[i][0]), a23 = ub2f(pa[1] & mlw[i][1]);
            f32x2 b01 = ub2f(pb[0] & mrw[i][0]), b23 = ub2f(pb[1] & mrw[i][1]);
            tl = (f32x4){a01.x, a01.y, a23.x, a23.y};
            tr = (f32x4){b01.x, b01.y, b23.x, b23.y};
          }
          const int wb = (dh + 1) * 3;
          acc += wf[i][wb]*tl + wf[i][wb+1]*tc + wf[i][wb+2]*tr;
        }
      }
      y[i] = relu4(acc + cdwv[i]);
    }
    f32x4 z[4];
    #pragma unroll
    for (int o = 0; o < 4; ++o) {
      f32x4 t = {c4v[o], c4v[o], c4v[o], c4v[o]};
      #pragma unroll
      for (int i2 = 0; i2 < 4; ++i2) t += w4f[o][i2]*y[i2];
      z[o] = relu4(t);
    }
    // memory order: [pix][o], 16 bf16 = 32B contiguous; quad index = h*24 + wq
    u32x4 s0 = { pk2(z[0].x,z[1].x), pk2(z[2].x,z[3].x), pk2(z[0].y,z[1].y), pk2(z[2].y,z[3].y) };
    u32x4 s1 = { pk2(z[0].z,z[1].z), pk2(z[2].z,z[3].z), pk2(z[0].w,z[1].w), pk2(z[2].w,z[3].w) };
    u32x4* dst = (u32x4*)(zbase + (size_t)(h*24 + wq)*16);
    dst[0] = s0;
    dst[1] = s1;
  }
}

// ---------------- kernel B: out = ReLU(Wo'' @ z2 + co), bf16 MFMA, m97 structure -----------
__global__ __launch_bounds__(256) void kB(const void* __restrict__ wopp_,
    const void* __restrict__ z2s_, const float* __restrict__ co, float* __restrict__ out)
{
  __shared__ alignas(16) char lA[20480];
  __shared__ alignas(16) char lB[16384];
  const char* wopp = (const char*)wopp_;
  const char* z2s  = (const char*)z2s_;

  const int tid = threadIdx.x;
  const int lane = tid & 63, wv = tid >> 6;
  const int wm = wv >> 1, wn = wv & 1;
  const int pt = blockIdx.x;      // 0..71 pixel tiles
  const int mt = blockIdx.y;      // 0..3  oc tiles
  const int b  = blockIdx.z;      // 0..7
  const int pix0 = pt * 128;
  const int l15 = lane & 15, lg = lane >> 4;

  f32x4 acc[4][4] = {};

  for (int kt = 0; kt < 8; ++kt) {
    const char* srcA = wopp + (size_t)(mt*8 + kt)*20480;
    for (int j = wv; j < 20; j += 4)
      gll16(srcA + j*1024 + lane*16, lA + j*1024);
    #pragma unroll
    for (int ct4 = 0; ct4 < 4; ++ct4) {
      int ct = wv*4 + ct4;
      const char* srcB = z2s + ((size_t)(b*128 + kt*16 + ct)*36864 + (size_t)pix0*4)*2;
      gll16(srcB + lane*16, lB + ct*1024);
    }
    __syncthreads();

    #pragma unroll
    for (int kk = 0; kk < 2; ++kk) {
      s16x8 af[4];
      #pragma unroll
      for (int m = 0; m < 4; ++m)
        af[m] = *(const s16x8*)(lA + kk*10240 + (wm*64 + m*16 + l15)*80 + lg*16);
      #pragma unroll
      for (int n = 0; n < 4; ++n) {
        const char* p = lB + kk*8192 + lg*2048 + (wn*64 + n*16 + l15)*8;
        s16x4 lo = *(const s16x4*)(p);
        s16x4 hi = *(const s16x4*)(p + 1024);
        s16x8 bfr = __builtin_shufflevector(lo, hi, 0,1,2,3,4,5,6,7);
        #pragma unroll
        for (int m = 0; m < 4; ++m)
          acc[m][n] = __builtin_amdgcn_mfma_f32_16x16x32_bf16(af[m], bfr, acc[m][n], 0, 0, 0);
      }
    }
    __syncthreads();
  }

  const int colp = pix0 + wn*64 + l15;
  #pragma unroll
  for (int m = 0; m < 4; ++m) {
    const int ocb = mt*128 + wm*64 + m*16 + lg*4;
    #pragma unroll
    for (int r2 = 0; r2 < 4; ++r2) {
      const int oc = ocb + r2;
      const float cov = co[oc];
      float* orow = out + ((size_t)(b*512 + oc))*9216 + colp;
      #pragma unroll
      for (int n = 0; n < 4; ++n) {
        float v = acc[m][n][r2] + cov;
        orow[(size_t)n*16] = fmaxf(v, 0.f);
      }
    }
  }
}

extern "C" void kernel_launch(void* const* d_in, const int* in_sizes, int n_in,
                              void* d_out, int out_size, void* d_ws, size_t ws_size,
                              hipStream_t stream)
{
  (void)in_sizes; (void)out_size;
  if (n_in < 19) return;
  const size_t Z2_BYTES = 75497472;      // 8*512*9216 bf16
  const size_t WOPP_BYTES = 655360;      // 32 chunks * 20480
  if (ws_size < Z2_BYTES + WOPP_BYTES + 2048) return;

  const float* x    = (const float*)d_in[0];
  const float* wdw  = (const float*)d_in[1];
  const float* bdw  = (const float*)d_in[2];
  const float* gdw  = (const float*)d_in[3];
  const float* bedw = (const float*)d_in[4];
  const float* mdw  = (const float*)d_in[5];
  const float* vdw  = (const float*)d_in[6];
  const float* w4   = (const float*)d_in[7];
  const float* bs   = (const float*)d_in[8];
  const float* gs   = (const float*)d_in[9];
  const float* bes  = (const float*)d_in[10];
  const float* ms   = (const float*)d_in[11];
  const float* vs   = (const float*)d_in[12];
  const float* wo   = (const float*)d_in[13];
  const float* bo   = (const float*)d_in[14];
  const float* go   = (const float*)d_in[15];
  const float* beo  = (const float*)d_in[16];
  const float* mo   = (const float*)d_in[17];
  const float* vo   = (const float*)d_in[18];

  __bf16* z2s  = (__bf16*)d_ws;
  __bf16* wopp = (__bf16*)((char*)d_ws + Z2_BYTES);
  float*  co   = (float*)((char*)d_ws + Z2_BYTES + WOPP_BYTES);

  kF<<<512, 512, 0, stream>>>(wo, bo, go, beo, mo, vo, wopp, co);
  kA<<<1024, 768, 0, stream>>>(x, wdw, bdw, gdw, bedw, mdw, vdw, w4, bs, gs, bes, ms, vs, z2s);
  kB<<<dim3(72, 4, 8), 256, 0, stream>>>(wopp, z2s, co, (float*)d_out);
}